// Round 4
// baseline (262.118 us; speedup 1.0000x reference)
//
#include <hip/hip_runtime.h>
#include <hip/hip_bf16.h>

#define HDIM 128

typedef __attribute__((ext_vector_type(8))) short short8;
typedef __attribute__((ext_vector_type(4))) float floatx4;

__device__ __forceinline__ float bf2f(unsigned short u) {
    return __uint_as_float(((unsigned)u) << 16);
}
__device__ __forceinline__ unsigned short f2b(float f) {
    __hip_bfloat16 h = __float2bfloat16(f);
    return __builtin_bit_cast(unsigned short, h);
}
__device__ __forceinline__ float ldv(const void* p, size_t i, int flag) {
    return flag ? bf2f(((const unsigned short*)p)[i]) : ((const float*)p)[i];
}
__device__ __forceinline__ short8 pack8(float4 a, float4 b) {
    short8 r;
    r[0] = (short)f2b(a.x); r[1] = (short)f2b(a.y);
    r[2] = (short)f2b(a.z); r[3] = (short)f2b(a.w);
    r[4] = (short)f2b(b.x); r[5] = (short)f2b(b.y);
    r[6] = (short)f2b(b.z); r[7] = (short)f2b(b.w);
    return r;
}

// ---------------------------------------------------------------------------
// Block-local dtype detect (identical result in every block; no cross-block
// dependency). flag=1 if bits look like bf16, 0 if f32 (low halves of f32
// are ~uniform u16 -> only ~58% plausible exponents vs ~100% for bf16).
// ---------------------------------------------------------------------------
__device__ __forceinline__ int local_detect(const unsigned short* zbits) {
    __shared__ int red[256];
    int tid = threadIdx.x;
    int cnt = 0;
    for (int i = tid; i < 4096; i += 256) {
        int ex = (zbits[i] >> 7) & 0xFF;
        if (ex >= 100 && ex <= 140) cnt++;
    }
    red[tid] = cnt;
    __syncthreads();
    for (int s = 128; s > 0; s >>= 1) {
        if (tid < s) red[tid] += red[tid + s];
        __syncthreads();
    }
    return (red[0] >= 3686) ? 1 : 0;
}

// ---------------------------------------------------------------------------
// prep: blocks 0-3 build swizzled, transposed 128x128 bf16 W images:
// img[b][n*128 + (g^(n&15))*8 + j] = w1[(part*128+g*8+j)*128 + n]
// b: 0=gd_top 1=gd_bot 2=gg_top 3=gg_bot.  Block 4: params to f32 + flag:
// [0:128)=b1_gd [128:256)=w2_gd [256:384)=b1_gg [384:512)=w2_gg
// [512]=b2_gd [513]=b2_gg
// ---------------------------------------------------------------------------
__global__ __launch_bounds__(256) void prep_kernel(
    const unsigned short* __restrict__ zbits,
    const void* __restrict__ w1_gd, const void* __restrict__ w1_gg,
    const void* __restrict__ b1_gd, const void* __restrict__ w2_gd,
    const void* __restrict__ b2_gd, const void* __restrict__ b1_gg,
    const void* __restrict__ w2_gg, const void* __restrict__ b2_gg,
    unsigned short* __restrict__ img, float* __restrict__ params,
    int* __restrict__ flagout)
{
    int flag = local_detect(zbits);
    int b = blockIdx.x;
    if (b < 4) {
        const void* w1 = (b < 2) ? w1_gd : w1_gg;
        int part = b & 1;
        unsigned short* out = img + b * 16384;
        for (int idx = threadIdx.x; idx < 16384; idx += 256) {
            int n   = idx >> 7;
            int rem = idx & 127;
            int g   = (rem >> 3) ^ (n & 15);
            int j   = rem & 7;
            size_t s = (size_t)(part * 128 + g * 8 + j) * 128 + n;
            out[idx] = flag ? ((const unsigned short*)w1)[s]
                            : f2b(((const float*)w1)[s]);
        }
    } else {
        int t = threadIdx.x;
        if (t < 128) {
            params[t]       = ldv(b1_gd, t, flag);
            params[256 + t] = ldv(b1_gg, t, flag);
        } else {
            params[t]       = ldv(w2_gd, t - 128, flag);
            params[256 + t] = ldv(w2_gg, t - 128, flag);
        }
        if (t == 0) {
            params[512] = ldv(b2_gd, 0, flag);
            params[513] = ldv(b2_gg, 0, flag);
            *flagout = flag;
        }
    }
}

// ---------------------------------------------------------------------------
// proj_all: one launch for all four 128x128 projections.
// Blocks [0, gblk): gene, 64 rows each, 3 phases vs same z fragments:
//   ph0: img0 -> A_gd (+b1_gd)  ph1: img2 -> A_gg (+b1_gg)  ph2: img3 -> B_gg
// Blocks [gblk, gblk+dblk): disease, 1 phase: img1 -> B_gd.
// W = MFMA A-operand (m = out col), Z = B-operand (n = out row); lane's 4
// accum regs = 4 consecutive out cols of one row -> ushort4 stores.
// b1 folded here so edge kernel needs no bias.
// ---------------------------------------------------------------------------
__global__ __launch_bounds__(256) void proj_all_kernel(
    const void* __restrict__ Zg, const void* __restrict__ Zd,
    const uint4* __restrict__ Wimg, const float* __restrict__ params,
    unsigned short* __restrict__ A_gd, unsigned short* __restrict__ B_gd,
    unsigned short* __restrict__ A_gg, unsigned short* __restrict__ B_gg,
    int NG, int ND, int gblk, const int* __restrict__ flagp)
{
    __shared__ uint4 sW[2048];  // 32 KB
    int tid  = threadIdx.x;
    int lane = tid & 63;
    int wave = tid >> 6;
    int nl   = lane & 15;
    int quad = lane >> 4;
    int flag = *flagp;

    bool gene = (int)blockIdx.x < gblk;
    int blk = gene ? blockIdx.x : blockIdx.x - gblk;
    int M = gene ? NG : ND;
    const void* Z = gene ? Zg : Zd;

    int row = blk * 64 + wave * 16 + nl;
    int rc = row < M ? row : (M - 1);

    short8 zf[4];
    if (flag) {
        const uint4* z = (const uint4*)Z + (size_t)rc * 16;
#pragma unroll
        for (int kc = 0; kc < 4; ++kc)
            zf[kc] = __builtin_bit_cast(short8, z[kc * 4 + quad]);
    } else {
        const float4* z = (const float4*)Z + (size_t)rc * 32;
#pragma unroll
        for (int kc = 0; kc < 4; ++kc) {
            int o = kc * 8 + quad * 2;
            zf[kc] = pack8(z[o], z[o + 1]);
        }
    }

    int nph = gene ? 3 : 1;
    for (int ph = 0; ph < nph; ++ph) {
        const uint4* im;
        unsigned short* Out;
        const float* bias;
        if (gene) {
            im   = Wimg + (ph == 0 ? 0 : ph == 1 ? 2 : 3) * 2048;
            Out  = ph == 0 ? A_gd : ph == 1 ? A_gg : B_gg;
            bias = ph == 0 ? params : ph == 1 ? params + 256 : nullptr;
        } else {
            im = Wimg + 2048; Out = B_gd; bias = nullptr;
        }
        __syncthreads();   // previous phase readers done before overwrite
#pragma unroll
        for (int i = 0; i < 8; ++i) sW[tid + i * 256] = im[tid + i * 256];
        __syncthreads();

        floatx4 acc[8];
#pragma unroll
        for (int nt = 0; nt < 8; ++nt) acc[nt] = (floatx4){0.f, 0.f, 0.f, 0.f};
#pragma unroll
        for (int kc = 0; kc < 4; ++kc) {
            int p = (kc * 4 + quad) ^ nl;   // undo XOR swizzle
#pragma unroll
            for (int nt = 0; nt < 8; ++nt) {
                short8 wf = __builtin_bit_cast(short8, sW[(nt * 16 + nl) * 16 + p]);
                acc[nt] = __builtin_amdgcn_mfma_f32_16x16x32_bf16(wf, zf[kc], acc[nt], 0, 0, 0);
            }
        }
        if (row < M) {
#pragma unroll
            for (int nt = 0; nt < 8; ++nt) {
                float4 bv = {0.f, 0.f, 0.f, 0.f};
                if (bias) bv = *(const float4*)(bias + nt * 16 + quad * 4);
                ushort4 v;
                v.x = f2b(acc[nt][0] + bv.x);
                v.y = f2b(acc[nt][1] + bv.y);
                v.z = f2b(acc[nt][2] + bv.z);
                v.w = f2b(acc[nt][3] + bv.w);
                *(ushort4*)(Out + (size_t)row * HDIM + nt * 16 + quad * 4) = v;
            }
        }
    }
}

// ---------------------------------------------------------------------------
// edge: one THREAD per edge. out[e] = relu(A[src]+B[dst]).w2 + b2
// (b1 pre-folded into A). rel is block-uniform -> w2/b2 via scalar loads.
// Per edge: 2 idx + 32 data (16B each) + 1 store lane-addresses.
// ---------------------------------------------------------------------------
__global__ __launch_bounds__(256) void edge_kernel(
    const int* __restrict__ edges_gd, const int* __restrict__ edges_gg,
    const unsigned short* __restrict__ A_gd, const unsigned short* __restrict__ B_gd,
    const unsigned short* __restrict__ A_gg, const unsigned short* __restrict__ B_gg,
    const float* __restrict__ params,
    void* __restrict__ out, int E, int nb, const int* __restrict__ flagp)
{
    int rel = ((int)blockIdx.x >= nb) ? 1 : 0;
    int e = (blockIdx.x - rel * nb) * 256 + threadIdx.x;
    if (e >= E) return;

    const int* edges = rel ? edges_gg : edges_gd;
    const unsigned short* A = rel ? A_gg : A_gd;
    const unsigned short* B = rel ? B_gg : B_gd;
    const float* w2 = params + 128 + rel * 256;   // block-uniform -> s_load
    float b2 = params[512 + rel];

    int src = edges[e];
    int dst = edges[E + e];
    const uint4* ar = (const uint4*)(A + (size_t)src * HDIM);
    const uint4* br = (const uint4*)(B + (size_t)dst * HDIM);

    float acc = 0.f;
#pragma unroll
    for (int g = 0; g < 4; ++g) {
        uint4 a[4], b[4];
#pragma unroll
        for (int i = 0; i < 4; ++i) { a[i] = ar[g * 4 + i]; b[i] = br[g * 4 + i]; }
#pragma unroll
        for (int i = 0; i < 4; ++i) {
            const unsigned* au = (const unsigned*)&a[i];
            const unsigned* bu = (const unsigned*)&b[i];
#pragma unroll
            for (int j = 0; j < 4; ++j) {
                int ch = g * 32 + i * 8 + j * 2;
                float x0 = __uint_as_float(au[j] << 16);
                float x1 = __uint_as_float(au[j] & 0xffff0000u);
                float y0 = __uint_as_float(bu[j] << 16);
                float y1 = __uint_as_float(bu[j] & 0xffff0000u);
                float h0 = fmaxf(x0 + y0, 0.f);
                float h1 = fmaxf(x1 + y1, 0.f);
                acc = fmaf(h0, w2[ch], acc);
                acc = fmaf(h1, w2[ch + 1], acc);
            }
        }
    }
    float r = acc + b2;
    size_t o = (size_t)rel * E + e;
    if (*flagp) ((unsigned short*)out)[o] = f2b(r);
    else        ((float*)out)[o] = r;
}

// ---------------------------------------------------------------------------
// Fallback path (ws too small): detect + full per-edge MLP, one edge/block.
// ---------------------------------------------------------------------------
__global__ __launch_bounds__(256) void detect_kernel(
    const unsigned short* __restrict__ zbits, int* __restrict__ flag)
{
    int f = local_detect(zbits);
    if (threadIdx.x == 0) *flag = f;
}

__global__ __launch_bounds__(128) void naive_edge_kernel(
    const int* __restrict__ edges,
    const void* __restrict__ zsrc, const void* __restrict__ zdst,
    const void* __restrict__ w1, const void* __restrict__ b1,
    const void* __restrict__ w2, const void* __restrict__ b2,
    void* __restrict__ out, size_t eoff, int E,
    const int* __restrict__ flagp)
{
    int flag = flagp ? *flagp : 0;
    __shared__ float zs[128], zd[128], red[128];
    int e = blockIdx.x;
    int n = threadIdx.x;
    int src = edges[e], dst = edges[E + e];
    zs[n] = ldv(zsrc, (size_t)src * HDIM + n, flag);
    zd[n] = ldv(zdst, (size_t)dst * HDIM + n, flag);
    __syncthreads();
    float acc = ldv(b1, n, flag);
    for (int k = 0; k < 128; ++k) acc = fmaf(zs[k], ldv(w1, (size_t)k * HDIM + n, flag), acc);
    for (int k = 0; k < 128; ++k) acc = fmaf(zd[k], ldv(w1, (size_t)(128 + k) * HDIM + n, flag), acc);
    red[n] = fmaxf(acc, 0.f) * ldv(w2, n, flag);
    __syncthreads();
    for (int s = 64; s > 0; s >>= 1) {
        if (n < s) red[n] += red[n + s];
        __syncthreads();
    }
    if (n == 0) {
        float r = red[0] + ldv(b2, 0, flag);
        if (flag) ((unsigned short*)out)[eoff + e] = f2b(r);
        else      ((float*)out)[eoff + e] = r;
    }
}

extern "C" void kernel_launch(void* const* d_in, const int* in_sizes, int n_in,
                              void* d_out, int out_size, void* d_ws, size_t ws_size,
                              hipStream_t stream)
{
    const void* z_gene = d_in[0];
    const void* z_dis  = d_in[1];
    const int* edges_gd = (const int*)d_in[2];
    const int* edges_gg = (const int*)d_in[3];
    const void* w1_gd = d_in[4];
    const void* b1_gd = d_in[5];
    const void* w2_gd = d_in[6];
    const void* b2_gd = d_in[7];
    const void* w1_gg = d_in[8];
    const void* b1_gg = d_in[9];
    const void* w2_gg = d_in[10];
    const void* b2_gg = d_in[11];

    int NG = in_sizes[0] / HDIM;   // 100000
    int ND = in_sizes[1] / HDIM;   // 20000
    int E  = in_sizes[2] / 2;      // 500000

    // workspace layout (bytes)
    size_t off_flag   = 0;
    size_t off_params = 256;
    size_t off_img    = 2560;
    size_t off_Agd    = off_img + 131072;
    size_t off_Bgd    = off_Agd + (size_t)NG * HDIM * 2;
    size_t off_Agg    = off_Bgd + (size_t)ND * HDIM * 2;
    size_t off_Bgg    = off_Agg + (size_t)NG * HDIM * 2;
    size_t need       = off_Bgg + (size_t)NG * HDIM * 2;

    char* ws = (char*)d_ws;

    if (ws_size < need) {
        const int* flagp = nullptr;
        if (ws_size >= 16) {
            detect_kernel<<<1, 256, 0, stream>>>((const unsigned short*)z_gene, (int*)ws);
            flagp = (const int*)ws;
        }
        naive_edge_kernel<<<E, 128, 0, stream>>>(edges_gd, z_gene, z_dis,
                                                 w1_gd, b1_gd, w2_gd, b2_gd,
                                                 d_out, 0, E, flagp);
        naive_edge_kernel<<<E, 128, 0, stream>>>(edges_gg, z_gene, z_gene,
                                                 w1_gg, b1_gg, w2_gg, b2_gg,
                                                 d_out, (size_t)E, E, flagp);
        return;
    }

    int* flag = (int*)(ws + off_flag);
    float* params = (float*)(ws + off_params);
    unsigned short* img = (unsigned short*)(ws + off_img);
    unsigned short* Agd = (unsigned short*)(ws + off_Agd);
    unsigned short* Bgd = (unsigned short*)(ws + off_Bgd);
    unsigned short* Agg = (unsigned short*)(ws + off_Agg);
    unsigned short* Bgg = (unsigned short*)(ws + off_Bgg);

    prep_kernel<<<5, 256, 0, stream>>>((const unsigned short*)z_gene,
                                       w1_gd, w1_gg, b1_gd, w2_gd, b2_gd,
                                       b1_gg, w2_gg, b2_gg, img, params, flag);

    const uint4* img4 = (const uint4*)img;
    int gblk = (NG + 63) / 64;   // 64 rows per block
    int dblk = (ND + 63) / 64;
    proj_all_kernel<<<gblk + dblk, 256, 0, stream>>>(z_gene, z_dis, img4, params,
                                                     Agd, Bgd, Agg, Bgg,
                                                     NG, ND, gblk, flag);

    int nb = (E + 255) / 256;
    edge_kernel<<<2 * nb, 256, 0, stream>>>(edges_gd, edges_gg, Agd, Bgd, Agg, Bgg,
                                            params, d_out, E, nb, flag);
}

// Round 5
// 226.552 us; speedup vs baseline: 1.1570x; 1.1570x over previous
//
#include <hip/hip_runtime.h>
#include <hip/hip_bf16.h>

#define HDIM 128

typedef __attribute__((ext_vector_type(8))) short short8;
typedef __attribute__((ext_vector_type(4))) float floatx4;

__device__ __forceinline__ float bf2f(unsigned short u) {
    return __uint_as_float(((unsigned)u) << 16);
}
__device__ __forceinline__ unsigned short f2b(float f) {
    __hip_bfloat16 h = __float2bfloat16(f);
    return __builtin_bit_cast(unsigned short, h);
}
__device__ __forceinline__ float ldv(const void* p, size_t i, int flag) {
    return flag ? bf2f(((const unsigned short*)p)[i]) : ((const float*)p)[i];
}
__device__ __forceinline__ short8 pack8(float4 a, float4 b) {
    short8 r;
    r[0] = (short)f2b(a.x); r[1] = (short)f2b(a.y);
    r[2] = (short)f2b(a.z); r[3] = (short)f2b(a.w);
    r[4] = (short)f2b(b.x); r[5] = (short)f2b(b.y);
    r[6] = (short)f2b(b.z); r[7] = (short)f2b(b.w);
    return r;
}

// ---------------------------------------------------------------------------
// Block-local dtype detect (same result in every block). flag=1 -> bf16,
// 0 -> f32 (low halves of f32 are ~uniform u16 -> ~58% plausible exponents).
// ---------------------------------------------------------------------------
__device__ __forceinline__ int local_detect(const unsigned short* zbits) {
    __shared__ int red[256];
    int tid = threadIdx.x;
    int cnt = 0;
    for (int i = tid; i < 4096; i += 256) {
        int ex = (zbits[i] >> 7) & 0xFF;
        if (ex >= 100 && ex <= 140) cnt++;
    }
    red[tid] = cnt;
    __syncthreads();
    for (int s = 128; s > 0; s >>= 1) {
        if (tid < s) red[tid] += red[tid + s];
        __syncthreads();
    }
    return (red[0] >= 3686) ? 1 : 0;
}

// ---------------------------------------------------------------------------
// prep: blocks 0-31 build swizzled transposed 128x128 bf16 W images with
// COALESCED source reads (consecutive threads read consecutive n for fixed k;
// scattered 2B writes are fire-and-forget). 8 blocks per image, 16 k each.
// img[im][n*128 + ((k>>3)^(n&15))*8 + (k&7)] = w1[(part*128+k)*128 + n]
// im: 0=gd_top 1=gd_bot 2=gg_top 3=gg_bot.  Block 32: params to f32 + flag:
// [0:128)=b1_gd [128:256)=w2_gd [256:384)=b1_gg [384:512)=w2_gg
// [512]=b2_gd [513]=b2_gg
// ---------------------------------------------------------------------------
__global__ __launch_bounds__(256) void prep_kernel(
    const unsigned short* __restrict__ zbits,
    const void* __restrict__ w1_gd, const void* __restrict__ w1_gg,
    const void* __restrict__ b1_gd, const void* __restrict__ w2_gd,
    const void* __restrict__ b2_gd, const void* __restrict__ b1_gg,
    const void* __restrict__ w2_gg, const void* __restrict__ b2_gg,
    unsigned short* __restrict__ img, float* __restrict__ params,
    int* __restrict__ flagout)
{
    int flag = local_detect(zbits);
    int b = blockIdx.x;
    int tid = threadIdx.x;
    if (b < 32) {
        int im   = b >> 3;          // image id
        int sub  = b & 7;           // 16 k-rows per sub-block
        const void* w1 = (im < 2) ? w1_gd : w1_gg;
        int part = im & 1;
        unsigned short* out = img + im * 16384;
        int n = tid & 127;
#pragma unroll
        for (int it = 0; it < 8; ++it) {
            int k = sub * 16 + it * 2 + (tid >> 7);
            unsigned short v = flag
                ? ((const unsigned short*)w1)[(size_t)(part * 128 + k) * 128 + n]
                : f2b(((const float*)w1)[(size_t)(part * 128 + k) * 128 + n]);
            out[n * 128 + (((k >> 3) ^ (n & 15)) << 3) + (k & 7)] = v;
        }
    } else {
        if (tid < 128) {
            params[tid]       = ldv(b1_gd, tid, flag);
            params[256 + tid] = ldv(b1_gg, tid, flag);
        } else {
            params[tid]       = ldv(w2_gd, tid - 128, flag);
            params[256 + tid] = ldv(w2_gg, tid - 128, flag);
        }
        if (tid == 0) {
            params[512] = ldv(b2_gd, 0, flag);
            params[513] = ldv(b2_gg, 0, flag);
            *flagout = flag;
        }
    }
}

// ---------------------------------------------------------------------------
// proj_all: all four 128x128 projections, one launch, 128 rows per block.
// Blocks [0,gblk): gene, 3 phases vs register-held z fragments:
//   ph0: img0 -> A_gd (+b1_gd)  ph1: img2 -> A_gg (+b1_gg)  ph2: img3 -> B_gg
// Blocks [gblk,gblk+dblk): disease, 1 phase: img1 -> B_gd.
// W = MFMA A-operand (m = out col), Z = B-operand (n = out row); lane's 4
// accum regs = 4 consecutive out cols of one row -> ushort4 stores.
// ---------------------------------------------------------------------------
__global__ __launch_bounds__(256) void proj_all_kernel(
    const void* __restrict__ Zg, const void* __restrict__ Zd,
    const uint4* __restrict__ Wimg, const float* __restrict__ params,
    unsigned short* __restrict__ A_gd, unsigned short* __restrict__ B_gd,
    unsigned short* __restrict__ A_gg, unsigned short* __restrict__ B_gg,
    int NG, int ND, int gblk, const int* __restrict__ flagp)
{
    __shared__ uint4 sW[2048];  // 32 KB
    int tid  = threadIdx.x;
    int lane = tid & 63;
    int wave = tid >> 6;
    int nl   = lane & 15;
    int quad = lane >> 4;
    int flag = *flagp;

    bool gene = (int)blockIdx.x < gblk;
    int blk = gene ? blockIdx.x : blockIdx.x - gblk;
    int M = gene ? NG : ND;
    const void* Z = gene ? Zg : Zd;

    int row0 = blk * 128 + wave * 32 + nl;
    int row1 = row0 + 16;
    int r0c = row0 < M ? row0 : (M - 1);
    int r1c = row1 < M ? row1 : (M - 1);

    short8 zf[2][4];
    if (flag) {
        const uint4* z0 = (const uint4*)Z + (size_t)r0c * 16;
        const uint4* z1 = (const uint4*)Z + (size_t)r1c * 16;
#pragma unroll
        for (int kc = 0; kc < 4; ++kc) {
            zf[0][kc] = __builtin_bit_cast(short8, z0[kc * 4 + quad]);
            zf[1][kc] = __builtin_bit_cast(short8, z1[kc * 4 + quad]);
        }
    } else {
        const float4* z0 = (const float4*)Z + (size_t)r0c * 32;
        const float4* z1 = (const float4*)Z + (size_t)r1c * 32;
#pragma unroll
        for (int kc = 0; kc < 4; ++kc) {
            int o = kc * 8 + quad * 2;
            zf[0][kc] = pack8(z0[o], z0[o + 1]);
            zf[1][kc] = pack8(z1[o], z1[o + 1]);
        }
    }

    int nph = gene ? 3 : 1;
    for (int ph = 0; ph < nph; ++ph) {
        const uint4* im;
        unsigned short* Out;
        const float* bias;
        if (gene) {
            im   = Wimg + (ph == 0 ? 0 : ph == 1 ? 2 : 3) * 2048;
            Out  = ph == 0 ? A_gd : ph == 1 ? A_gg : B_gg;
            bias = ph == 0 ? params : ph == 1 ? params + 256 : nullptr;
        } else {
            im = Wimg + 2048; Out = B_gd; bias = nullptr;
        }
        __syncthreads();   // previous phase readers done before overwrite
#pragma unroll
        for (int i = 0; i < 8; ++i) sW[tid + i * 256] = im[tid + i * 256];
        __syncthreads();

        floatx4 acc[2][8];
#pragma unroll
        for (int rt = 0; rt < 2; ++rt)
#pragma unroll
            for (int nt = 0; nt < 8; ++nt)
                acc[rt][nt] = (floatx4){0.f, 0.f, 0.f, 0.f};

#pragma unroll
        for (int kc = 0; kc < 4; ++kc) {
            int p = (kc * 4 + quad) ^ nl;   // undo XOR swizzle
#pragma unroll
            for (int nt = 0; nt < 8; ++nt) {
                short8 wf = __builtin_bit_cast(short8, sW[(nt * 16 + nl) * 16 + p]);
                acc[0][nt] = __builtin_amdgcn_mfma_f32_16x16x32_bf16(wf, zf[0][kc], acc[0][nt], 0, 0, 0);
                acc[1][nt] = __builtin_amdgcn_mfma_f32_16x16x32_bf16(wf, zf[1][kc], acc[1][nt], 0, 0, 0);
            }
        }
#pragma unroll
        for (int rt = 0; rt < 2; ++rt) {
            int row = rt ? row1 : row0;
            if (row < M) {
#pragma unroll
                for (int nt = 0; nt < 8; ++nt) {
                    float4 bv = {0.f, 0.f, 0.f, 0.f};
                    if (bias) bv = *(const float4*)(bias + nt * 16 + quad * 4);
                    ushort4 v;
                    v.x = f2b(acc[rt][nt][0] + bv.x);
                    v.y = f2b(acc[rt][nt][1] + bv.y);
                    v.z = f2b(acc[rt][nt][2] + bv.z);
                    v.w = f2b(acc[rt][nt][3] + bv.w);
                    *(ushort4*)(Out + (size_t)row * HDIM + nt * 16 + quad * 4) = v;
                }
            }
        }
    }
}

// ---------------------------------------------------------------------------
// edge: 8 lanes/edge, 2 edges per lane-group (8 outstanding 16B data loads
// per lane). out[e] = relu(A[src]+B[dst]).w2 + b2  (b1 pre-folded into A).
// rel block-uniform -> w2/b2 scalar; idx as one int2 pair per 2 edges.
// Clamped loads (no divergence), guarded stores.
// ---------------------------------------------------------------------------
__global__ __launch_bounds__(256) void edge_kernel(
    const int* __restrict__ edges_gd, const int* __restrict__ edges_gg,
    const unsigned short* __restrict__ A_gd, const unsigned short* __restrict__ B_gd,
    const unsigned short* __restrict__ A_gg, const unsigned short* __restrict__ B_gg,
    const float* __restrict__ params,
    void* __restrict__ out, int E, int nb, const int* __restrict__ flagp)
{
    int rel = ((int)blockIdx.x >= nb) ? 1 : 0;
    int blk = blockIdx.x - rel * nb;
    const int* edges = rel ? edges_gg : edges_gd;
    const unsigned short* A = rel ? A_gg : A_gd;
    const unsigned short* B = rel ? B_gg : B_gd;
    const float* w2 = params + 128 + rel * 256;   // block-uniform
    float b2 = params[512 + rel];

    int tid  = threadIdx.x;
    int lane = tid & 63;
    int wave = tid >> 6;
    int nl   = lane & 7;    // lane within edge-group
    int grp  = lane >> 3;   // 8 groups per wave

    // per-lane w2 slice: channels [nl*16, nl*16+16)
    float w2f[16];
#pragma unroll
    for (int i = 0; i < 4; ++i) {
        float4 t = *(const float4*)(w2 + nl * 16 + i * 4);
        w2f[i * 4 + 0] = t.x; w2f[i * 4 + 1] = t.y;
        w2f[i * 4 + 2] = t.z; w2f[i * 4 + 3] = t.w;
    }

    int e0 = blk * 64 + (wave * 8 + grp) * 2;
    int e1 = e0 + 1;
    int emax = E - 2 > 0 ? E - 2 : 0;
    int ec = e0 < emax ? e0 : emax;     // clamped pair base (in-bounds int2)
    int sel = e0 - ec;                  // 0 normally; 1 only on odd tail
    int2 sp = *(const int2*)(edges + ec);
    int2 dp = *(const int2*)(edges + E + ec);
    int src0 = sel ? sp.y : sp.x;
    int dst0 = sel ? dp.y : dp.x;
    int src1 = sp.y;
    int dst1 = dp.y;

    const uint4* a0p = (const uint4*)(A + (size_t)src0 * HDIM) + nl * 2;
    const uint4* b0p = (const uint4*)(B + (size_t)dst0 * HDIM) + nl * 2;
    const uint4* a1p = (const uint4*)(A + (size_t)src1 * HDIM) + nl * 2;
    const uint4* b1p = (const uint4*)(B + (size_t)dst1 * HDIM) + nl * 2;
    uint4 a0[2] = {a0p[0], a0p[1]};
    uint4 c0[2] = {b0p[0], b0p[1]};
    uint4 a1[2] = {a1p[0], a1p[1]};
    uint4 c1[2] = {b1p[0], b1p[1]};

    float acc0 = 0.f, acc1 = 0.f;
#pragma unroll
    for (int i = 0; i < 2; ++i) {
        const unsigned* au0 = (const unsigned*)&a0[i];
        const unsigned* cu0 = (const unsigned*)&c0[i];
        const unsigned* au1 = (const unsigned*)&a1[i];
        const unsigned* cu1 = (const unsigned*)&c1[i];
#pragma unroll
        for (int j = 0; j < 4; ++j) {
            int ch = i * 8 + j * 2;
            float x0 = __uint_as_float(au0[j] << 16);
            float x1 = __uint_as_float(au0[j] & 0xffff0000u);
            float y0 = __uint_as_float(cu0[j] << 16);
            float y1 = __uint_as_float(cu0[j] & 0xffff0000u);
            acc0 = fmaf(fmaxf(x0 + y0, 0.f), w2f[ch], acc0);
            acc0 = fmaf(fmaxf(x1 + y1, 0.f), w2f[ch + 1], acc0);
            float u0 = __uint_as_float(au1[j] << 16);
            float u1 = __uint_as_float(au1[j] & 0xffff0000u);
            float v0 = __uint_as_float(cu1[j] << 16);
            float v1 = __uint_as_float(cu1[j] & 0xffff0000u);
            acc1 = fmaf(fmaxf(u0 + v0, 0.f), w2f[ch], acc1);
            acc1 = fmaf(fmaxf(u1 + v1, 0.f), w2f[ch + 1], acc1);
        }
    }
    acc0 += __shfl_xor(acc0, 1); acc1 += __shfl_xor(acc1, 1);
    acc0 += __shfl_xor(acc0, 2); acc1 += __shfl_xor(acc1, 2);
    acc0 += __shfl_xor(acc0, 4); acc1 += __shfl_xor(acc1, 4);

    if (nl == 0) {
        int flag = *flagp;
        size_t base = (size_t)rel * E;
        if (e0 < E) {
            float r = acc0 + b2;
            if (flag) ((unsigned short*)out)[base + e0] = f2b(r);
            else      ((float*)out)[base + e0] = r;
        }
        if (e1 < E) {
            float r = acc1 + b2;
            if (flag) ((unsigned short*)out)[base + e1] = f2b(r);
            else      ((float*)out)[base + e1] = r;
        }
    }
}

// ---------------------------------------------------------------------------
// Fallback path (ws too small): detect + full per-edge MLP, one edge/block.
// ---------------------------------------------------------------------------
__global__ __launch_bounds__(256) void detect_kernel(
    const unsigned short* __restrict__ zbits, int* __restrict__ flag)
{
    int f = local_detect(zbits);
    if (threadIdx.x == 0) *flag = f;
}

__global__ __launch_bounds__(128) void naive_edge_kernel(
    const int* __restrict__ edges,
    const void* __restrict__ zsrc, const void* __restrict__ zdst,
    const void* __restrict__ w1, const void* __restrict__ b1,
    const void* __restrict__ w2, const void* __restrict__ b2,
    void* __restrict__ out, size_t eoff, int E,
    const int* __restrict__ flagp)
{
    int flag = flagp ? *flagp : 0;
    __shared__ float zs[128], zd[128], red[128];
    int e = blockIdx.x;
    int n = threadIdx.x;
    int src = edges[e], dst = edges[E + e];
    zs[n] = ldv(zsrc, (size_t)src * HDIM + n, flag);
    zd[n] = ldv(zdst, (size_t)dst * HDIM + n, flag);
    __syncthreads();
    float acc = ldv(b1, n, flag);
    for (int k = 0; k < 128; ++k) acc = fmaf(zs[k], ldv(w1, (size_t)k * HDIM + n, flag), acc);
    for (int k = 0; k < 128; ++k) acc = fmaf(zd[k], ldv(w1, (size_t)(128 + k) * HDIM + n, flag), acc);
    red[n] = fmaxf(acc, 0.f) * ldv(w2, n, flag);
    __syncthreads();
    for (int s = 64; s > 0; s >>= 1) {
        if (n < s) red[n] += red[n + s];
        __syncthreads();
    }
    if (n == 0) {
        float r = red[0] + ldv(b2, 0, flag);
        if (flag) ((unsigned short*)out)[eoff + e] = f2b(r);
        else      ((float*)out)[eoff + e] = r;
    }
}

extern "C" void kernel_launch(void* const* d_in, const int* in_sizes, int n_in,
                              void* d_out, int out_size, void* d_ws, size_t ws_size,
                              hipStream_t stream)
{
    const void* z_gene = d_in[0];
    const void* z_dis  = d_in[1];
    const int* edges_gd = (const int*)d_in[2];
    const int* edges_gg = (const int*)d_in[3];
    const void* w1_gd = d_in[4];
    const void* b1_gd = d_in[5];
    const void* w2_gd = d_in[6];
    const void* b2_gd = d_in[7];
    const void* w1_gg = d_in[8];
    const void* b1_gg = d_in[9];
    const void* w2_gg = d_in[10];
    const void* b2_gg = d_in[11];

    int NG = in_sizes[0] / HDIM;   // 100000
    int ND = in_sizes[1] / HDIM;   // 20000
    int E  = in_sizes[2] / 2;      // 500000

    // workspace layout (bytes)
    size_t off_flag   = 0;
    size_t off_params = 256;
    size_t off_img    = 2560;
    size_t off_Agd    = off_img + 131072;
    size_t off_Bgd    = off_Agd + (size_t)NG * HDIM * 2;
    size_t off_Agg    = off_Bgd + (size_t)ND * HDIM * 2;
    size_t off_Bgg    = off_Agg + (size_t)NG * HDIM * 2;
    size_t need       = off_Bgg + (size_t)NG * HDIM * 2;

    char* ws = (char*)d_ws;

    if (ws_size < need) {
        const int* flagp = nullptr;
        if (ws_size >= 16) {
            detect_kernel<<<1, 256, 0, stream>>>((const unsigned short*)z_gene, (int*)ws);
            flagp = (const int*)ws;
        }
        naive_edge_kernel<<<E, 128, 0, stream>>>(edges_gd, z_gene, z_dis,
                                                 w1_gd, b1_gd, w2_gd, b2_gd,
                                                 d_out, 0, E, flagp);
        naive_edge_kernel<<<E, 128, 0, stream>>>(edges_gg, z_gene, z_gene,
                                                 w1_gg, b1_gg, w2_gg, b2_gg,
                                                 d_out, (size_t)E, E, flagp);
        return;
    }

    int* flag = (int*)(ws + off_flag);
    float* params = (float*)(ws + off_params);
    unsigned short* img = (unsigned short*)(ws + off_img);
    unsigned short* Agd = (unsigned short*)(ws + off_Agd);
    unsigned short* Bgd = (unsigned short*)(ws + off_Bgd);
    unsigned short* Agg = (unsigned short*)(ws + off_Agg);
    unsigned short* Bgg = (unsigned short*)(ws + off_Bgg);

    prep_kernel<<<33, 256, 0, stream>>>((const unsigned short*)z_gene,
                                        w1_gd, w1_gg, b1_gd, w2_gd, b2_gd,
                                        b1_gg, w2_gg, b2_gg, img, params, flag);

    const uint4* img4 = (const uint4*)img;
    int gblk = (NG + 127) / 128;
    int dblk = (ND + 127) / 128;
    proj_all_kernel<<<gblk + dblk, 256, 0, stream>>>(z_gene, z_dis, img4, params,
                                                     Agd, Bgd, Agg, Bgg,
                                                     NG, ND, gblk, flag);

    int nb = (E + 63) / 64;
    edge_kernel<<<2 * nb, 256, 0, stream>>>(edges_gd, edges_gg, Agd, Bgd, Agg, Bgg,
                                            params, d_out, E, nb, flag);
}